// Round 5
// baseline (342.758 us; speedup 1.0000x reference)
//
#include <hip/hip_runtime.h>
#include <hip/hip_bf16.h>

typedef __attribute__((ext_vector_type(8))) short bf16x8;
typedef __attribute__((ext_vector_type(4))) float f32x4;

// ---------------- helpers ----------------

__device__ __forceinline__ ushort f2bf(float f) {
    unsigned int b = __float_as_uint(f);
    unsigned int r = (b + 0x7fffu + ((b >> 16) & 1u)) >> 16;  // RNE
    return (ushort)r;
}
__device__ __forceinline__ float bflo(uint v) { return __uint_as_float(v << 16); }
__device__ __forceinline__ float bfhi(uint v) { return __uint_as_float(v & 0xffff0000u); }

// ---------------- CSR build ----------------

// count in-degree AND record each edge's rank within its dst bucket
__global__ void count_kernel(const int* __restrict__ dst, int* __restrict__ cnt,
                             int* __restrict__ rank, int E) {
    int stride = gridDim.x * blockDim.x;
    for (int e = blockIdx.x * blockDim.x + threadIdx.x; e < E; e += stride)
        rank[e] = atomicAdd(&cnt[dst[e]], 1);
}

__global__ __launch_bounds__(1024) void scan_part(const int* __restrict__ cnt,
                                                  int* __restrict__ bsum, int Nn) {
    int i = blockIdx.x * 1024 + threadIdx.x;
    int v = (i < Nn) ? cnt[i] : 0;
#pragma unroll
    for (int d = 1; d < 64; d <<= 1) v += __shfl_xor(v, d, 64);
    __shared__ int wsums[16];
    if ((threadIdx.x & 63) == 0) wsums[threadIdx.x >> 6] = v;
    __syncthreads();
    if (threadIdx.x == 0) {
        int s = 0;
        for (int w = 0; w < 16; ++w) s += wsums[w];
        bsum[blockIdx.x] = s;
    }
}

// parallel exclusive scan over NB<=128 block sums (1 block, 128 threads)
__global__ __launch_bounds__(128) void scan_top(int* __restrict__ bsum, int NB) {
    int i = threadIdx.x;
    int v = (i < NB) ? bsum[i] : 0;
    int x = v;
#pragma unroll
    for (int d = 1; d < 64; d <<= 1) {
        int y = __shfl_up(x, d, 64);
        if ((i & 63) >= d) x += y;
    }
    __shared__ int w0;
    if (i == 63) w0 = x;
    __syncthreads();
    if (i >= 64) x += w0;
    if (i < NB) bsum[i] = x - v;
}

__global__ __launch_bounds__(1024) void scan_final(const int* __restrict__ cnt,
                                                   const int* __restrict__ bpre,
                                                   int* __restrict__ offs,
                                                   float* __restrict__ dis, int Nn, int E) {
    int i = blockIdx.x * 1024 + threadIdx.x;
    int v = (i < Nn) ? cnt[i] : 0;
    int lane = threadIdx.x & 63, wid = threadIdx.x >> 6;
    int x = v;
#pragma unroll
    for (int d = 1; d < 64; d <<= 1) {
        int y = __shfl_up(x, d, 64);
        if (lane >= d) x += y;
    }
    __shared__ int wsum[16];
    __shared__ int wpre[16];
    if (lane == 63) wsum[wid] = x;
    __syncthreads();
    if (threadIdx.x == 0) {
        int run = 0;
        for (int w = 0; w < 16; ++w) { wpre[w] = run; run += wsum[w]; }
    }
    __syncthreads();
    int excl = x - v + wpre[wid] + bpre[blockIdx.x];
    if (i < Nn) {
        offs[i] = excl;
        dis[i] = rsqrtf((float)v + 1.0f);
    }
    if (blockIdx.x == 0 && threadIdx.x == 0) offs[Nn] = E;
}

// atomic-free bucket fill: position = offs[dst] + rank
__global__ void fill_kernel(const int* __restrict__ src, const int* __restrict__ dst,
                            const int* __restrict__ rank, const int* __restrict__ offs,
                            int* __restrict__ rec, int E) {
    int stride = gridDim.x * blockDim.x;
    for (int e = blockIdx.x * blockDim.x + threadIdx.x; e < E; e += stride)
        rec[offs[dst[e]] + rank[e]] = src[e];
}

// ---------------- casts ----------------

// tbl[s][c] = bf16(dis[s] * emb[s][c]); processes float4 chunks, 32 chunks/row
__global__ void cast_scale_kernel(const float4* __restrict__ in, const float* __restrict__ dis,
                                  ushort4* __restrict__ out, int n4) {
    int stride = gridDim.x * blockDim.x;
    for (int i = blockIdx.x * blockDim.x + threadIdx.x; i < n4; i += stride) {
        float s = dis[i >> 5];
        float4 v = in[i];
        ushort4 o;
        o.x = f2bf(v.x * s); o.y = f2bf(v.y * s); o.z = f2bf(v.z * s); o.w = f2bf(v.w * s);
        out[i] = o;
    }
}

// Wt[n][k] = bf16(W[k][n]); total = Kd*Nd elements, Wt is [Nd][Kd]
__global__ void castT_kernel(const float* __restrict__ W, ushort* __restrict__ Wt, int Kd, int Nd) {
    int i = blockIdx.x * 256 + threadIdx.x;
    if (i >= Kd * Nd) return;
    int n = i / Kd, k = i % Kd;
    Wt[i] = f2bf(W[(size_t)k * Nd + n]);
}

// ---------------- aggregation over 128 bf16 cols (pre-scaled table) ----------------
// tbl[s] = dis[s]*x[s] (bf16). out = dn * (tbl[gw] + sum_e tbl[rec[e]])  (+bias)
// one wave per node; lane owns cols {2*lane, 2*lane+1} packed in one uint.
// 8-wide edge batching; tail edges zeroed with one cndmask.

template <bool BIAS, bool BF16OUT>
__global__ __launch_bounds__(256) void agg_kernel(const uint* __restrict__ tbl,   // [Nn][64]
                                                  const int* __restrict__ offs,
                                                  const int* __restrict__ rec,    // src per edge
                                                  const float* __restrict__ dis,
                                                  const float* __restrict__ bias,
                                                  void* __restrict__ outp, int Nn) {
    int gw = (int)((blockIdx.x * 256 + threadIdx.x) >> 6);
    uint lane = threadIdx.x & 63;
    if (gw >= Nn) return;
    float dn = dis[gw];
    int e0 = offs[gw], e1 = offs[gw + 1];
    uint hv = tbl[(uint)gw * 64u + lane];
    float ax = bflo(hv), ay = bfhi(hv);

    for (int base = e0; base < e1; base += 8) {
        uint idx[8];
#pragma unroll
        for (int j = 0; j < 8; ++j) {
            int e = base + j;
            idx[j] = (uint)rec[e < e1 ? e : e1 - 1];
        }
        uint vv[8];
#pragma unroll
        for (int j = 0; j < 8; ++j) vv[j] = tbl[idx[j] * 64u + lane];
#pragma unroll
        for (int j = 0; j < 8; ++j) {
            uint v = (base + j < e1) ? vv[j] : 0u;
            ax += bflo(v);
            ay += bfhi(v);
        }
    }

    ax *= dn; ay *= dn;
    if (BIAS) {
        float2 bv = reinterpret_cast<const float2*>(bias)[lane];
        ax += bv.x; ay += bv.y;
    }
    if (BF16OUT) {
        reinterpret_cast<uint*>(outp)[(uint)gw * 64u + lane] =
            (uint)f2bf(ax) | ((uint)f2bf(ay) << 16);
    } else {
        float2 o; o.x = ax; o.y = ay;
        reinterpret_cast<float2*>(outp)[(uint)gw * 64u + lane] = o;
    }
}

// ---------------- MFMA GEMM: C[M,N] = A[M,K] @ W[K,N], A bf16 row-major, Wt[n][k] bf16 ----------------
// block = 4 waves, tile 64 rows x N cols; wave w owns cols [w*N/4, (w+1)*N/4).
// mfma_f32_16x16x32_bf16: C/D col=lane&15, row=(lane>>4)*4+reg  [measured m89].
// FIN: add bias, L2-normalize rows (cross-wave via LDS), write bf16.
// SCALE: multiply row r by dsc[r] before writing bf16 (pre-scaled gather table).

template <int K, int N, bool FIN, bool SCALE>
__global__ __launch_bounds__(256) void mfma_gemm(const ushort* __restrict__ A,
                                                 const ushort* __restrict__ Wt,
                                                 const float* __restrict__ bias,
                                                 const float* __restrict__ dsc,
                                                 ushort* __restrict__ Cb, int M) {
    constexpr int NS = N / 64;   // n-subtiles per wave
    constexpr int KS = K / 32;   // k-steps
    int lane = threadIdx.x & 63, wid = threadIdx.x >> 6;
    int m0 = blockIdx.x * 64;
    int koff = (lane >> 4) * 8;

    const bf16x8* ap[4];
#pragma unroll
    for (int ms = 0; ms < 4; ++ms) {
        int r = m0 + ms * 16 + (lane & 15);
        if (r >= M) r = M - 1;
        ap[ms] = reinterpret_cast<const bf16x8*>(A + (size_t)r * K + koff);
    }
    const bf16x8* bp[NS];
#pragma unroll
    for (int ns = 0; ns < NS; ++ns) {
        int c = wid * (N / 4) + ns * 16 + (lane & 15);
        bp[ns] = reinterpret_cast<const bf16x8*>(Wt + (size_t)c * K + koff);
    }

    f32x4 acc[4][NS];
#pragma unroll
    for (int ms = 0; ms < 4; ++ms)
#pragma unroll
        for (int ns = 0; ns < NS; ++ns) acc[ms][ns] = (f32x4){0.f, 0.f, 0.f, 0.f};

#pragma unroll
    for (int ks = 0; ks < KS; ++ks) {
        bf16x8 a[4], b[NS];
#pragma unroll
        for (int ms = 0; ms < 4; ++ms) a[ms] = ap[ms][ks * 4];
#pragma unroll
        for (int ns = 0; ns < NS; ++ns) b[ns] = bp[ns][ks * 4];
#pragma unroll
        for (int ms = 0; ms < 4; ++ms)
#pragma unroll
            for (int ns = 0; ns < NS; ++ns)
                acc[ms][ns] = __builtin_amdgcn_mfma_f32_16x16x32_bf16(a[ms], b[ns], acc[ms][ns], 0, 0, 0);
    }

    if (FIN) {
        float bv[NS];
#pragma unroll
        for (int ns = 0; ns < NS; ++ns) bv[ns] = bias[wid * (N / 4) + ns * 16 + (lane & 15)];
        float ps[4][4];
#pragma unroll
        for (int ms = 0; ms < 4; ++ms)
#pragma unroll
            for (int r = 0; r < 4; ++r) {
                float s = 0.f;
#pragma unroll
                for (int ns = 0; ns < NS; ++ns) {
                    float v = acc[ms][ns][r] + bv[ns];
                    acc[ms][ns][r] = v;
                    s += v * v;
                }
                ps[ms][r] = s;
            }
#pragma unroll
        for (int d = 1; d < 16; d <<= 1)
#pragma unroll
            for (int ms = 0; ms < 4; ++ms)
#pragma unroll
                for (int r = 0; r < 4; ++r) ps[ms][r] += __shfl_xor(ps[ms][r], d, 64);
        __shared__ float ssl[4][64];
        if ((lane & 15) == 0) {
#pragma unroll
            for (int ms = 0; ms < 4; ++ms)
#pragma unroll
                for (int r = 0; r < 4; ++r) ssl[wid][ms * 16 + (lane >> 4) * 4 + r] = ps[ms][r];
        }
        __syncthreads();
#pragma unroll
        for (int ms = 0; ms < 4; ++ms)
#pragma unroll
            for (int r = 0; r < 4; ++r) {
                int rt = ms * 16 + (lane >> 4) * 4 + r;
                float tot = ssl[0][rt] + ssl[1][rt] + ssl[2][rt] + ssl[3][rt];
                float inv = 1.0f / fmaxf(sqrtf(tot), 1e-12f);
                int row = m0 + rt;
                if (row < M) {
#pragma unroll
                    for (int ns = 0; ns < NS; ++ns)
                        Cb[(size_t)row * N + wid * (N / 4) + ns * 16 + (lane & 15)] =
                            f2bf(acc[ms][ns][r] * inv);
                }
            }
    } else {
#pragma unroll
        for (int ms = 0; ms < 4; ++ms)
#pragma unroll
            for (int r = 0; r < 4; ++r) {
                int row = m0 + ms * 16 + (lane >> 4) * 4 + r;
                if (row < M) {
                    float sc = SCALE ? dsc[row] : 1.0f;
#pragma unroll
                    for (int ns = 0; ns < NS; ++ns)
                        Cb[(size_t)row * N + wid * (N / 4) + ns * 16 + (lane & 15)] =
                            f2bf(acc[ms][ns][r] * sc);
                }
            }
    }
}

// ---------------- launch ----------------

extern "C" void kernel_launch(void* const* d_in, const int* in_sizes, int n_in,
                              void* d_out, int out_size, void* d_ws, size_t ws_size,
                              hipStream_t stream) {
    const float* emb = (const float*)d_in[0];
    const float* W1 = (const float*)d_in[1];
    const float* b1 = (const float*)d_in[2];
    const float* W2 = (const float*)d_in[3];
    const float* b2 = (const float*)d_in[4];
    const int* eidx = (const int*)d_in[5];

    const int Nn = in_sizes[0] / 128;   // 100000
    const int E = in_sizes[5] / 2;      // 1600000
    const int* srcp = eidx;
    const int* dstp = eidx + E;

    float* ws = (float*)d_ws;
    size_t o = 0;
    uint* tbl1 = (uint*)(ws + o);  o += (size_t)Nn * 64;   // dis*emb bf16 [Nn][128]
    uint* axb = (uint*)(ws + o);   o += (size_t)Nn * 64;   // agg1 out bf16 [Nn][128]
    uint* xbb = (uint*)(ws + o);   o += (size_t)Nn * 128;  // layer1 out bf16 [Nn][256]
    uint* tbl2 = (uint*)(ws + o);  o += (size_t)Nn * 64;   // dis*h2 bf16 [Nn][128]
    ushort* W1t = (ushort*)(ws + o); o += 128 * 256 / 2;   // [256][128]
    ushort* W2t = (ushort*)(ws + o); o += 256 * 128 / 2;   // [128][256]
    float* dis = ws + o;    o += Nn;
    int* cnt = (int*)(ws + o);    o += Nn;
    int* offs = (int*)(ws + o);   o += Nn + 16;
    int* bsum = (int*)(ws + o);   o += 128;
    int* rank = (int*)(ws + o);   o += E;
    int* rec = (int*)(ws + o);    o += E;

    hipMemsetAsync(cnt, 0, (size_t)Nn * sizeof(int), stream);

    count_kernel<<<2048, 256, 0, stream>>>(dstp, cnt, rank, E);
    int NB = (Nn + 1023) / 1024;  // 98
    scan_part<<<NB, 1024, 0, stream>>>(cnt, bsum, Nn);
    scan_top<<<1, 128, 0, stream>>>(bsum, NB);
    scan_final<<<NB, 1024, 0, stream>>>(cnt, bsum, offs, dis, Nn, E);
    fill_kernel<<<2048, 256, 0, stream>>>(srcp, dstp, rank, offs, rec, E);

    // casts (cast_scale needs dis -> after scan_final)
    cast_scale_kernel<<<2048, 256, 0, stream>>>((const float4*)emb, dis, (ushort4*)tbl1, Nn * 128 / 4);
    castT_kernel<<<(128 * 256 + 255) / 256, 256, 0, stream>>>(W1, W1t, 128, 256);
    castT_kernel<<<(256 * 128 + 255) / 256, 256, 0, stream>>>(W2, W2t, 256, 128);

    // layer 1: aggregate pre-scaled emb (bf16 out), GEMM 128->256 + bias + L2 norm (bf16 out)
    agg_kernel<false, true><<<(Nn + 3) / 4, 256, 0, stream>>>(tbl1, offs, rec, dis, nullptr, axb, Nn);
    mfma_gemm<128, 256, true, false><<<(Nn + 63) / 64, 256, 0, stream>>>((const ushort*)axb, W1t, b1, nullptr, (ushort*)xbb, Nn);

    // layer 2: GEMM 256->128 (bf16 out, rows pre-scaled by dis), aggregate + bias (fp32 out)
    mfma_gemm<256, 128, false, true><<<(Nn + 63) / 64, 256, 0, stream>>>((const ushort*)xbb, W2t, nullptr, dis, (ushort*)tbl2, Nn);
    agg_kernel<true, false><<<(Nn + 3) / 4, 256, 0, stream>>>(tbl2, offs, rec, dis, b2, d_out, Nn);
}

// Round 6
// 309.252 us; speedup vs baseline: 1.1083x; 1.1083x over previous
//
#include <hip/hip_runtime.h>
#include <hip/hip_bf16.h>

typedef __attribute__((ext_vector_type(8))) short bf16x8;
typedef __attribute__((ext_vector_type(4))) float f32x4;

// ---------------- helpers ----------------

__device__ __forceinline__ ushort f2bf(float f) {
    unsigned int b = __float_as_uint(f);
    unsigned int r = (b + 0x7fffu + ((b >> 16) & 1u)) >> 16;  // RNE
    return (ushort)r;
}
__device__ __forceinline__ float bflo(uint v) { return __uint_as_float(v << 16); }
__device__ __forceinline__ float bfhi(uint v) { return __uint_as_float(v & 0xffff0000u); }

// ---------------- prep: zero cnt + transpose-cast both weights ----------------
// blocks [0,zb): zero cnt; [zb,zb+128): W1t; [zb+128,zb+256): W2t

__global__ __launch_bounds__(256) void prep_kernel(const float* __restrict__ W1, ushort* __restrict__ W1t,
                                                   const float* __restrict__ W2, ushort* __restrict__ W2t,
                                                   int* __restrict__ cnt, int Nn, int zb) {
    int b = blockIdx.x, t = threadIdx.x;
    if (b < zb) {
        int i = b * 256 + t;
        if (i < Nn) cnt[i] = 0;
    } else if (b < zb + 128) {
        int i = (b - zb) * 256 + t;            // 32768 = 128*256 elems, W1t[n][k], n in [0,256), k in [0,128)
        int n = i >> 7, k = i & 127;
        W1t[i] = f2bf(W1[(size_t)k * 256 + n]);
    } else {
        int i = (b - zb - 128) * 256 + t;      // W2t[n][k], n in [0,128), k in [0,256)
        int n = i >> 8, k = i & 255;
        W2t[i] = f2bf(W2[(size_t)k * 128 + n]);
    }
}

// ---------------- CSR build ----------------

// 4 edges/thread: 4 independent atomics in flight, then 4 rank stores
__global__ void count_kernel(const int* __restrict__ dst, int* __restrict__ cnt,
                             int* __restrict__ rank, int E) {
    int i = blockIdx.x * blockDim.x + threadIdx.x;
    int e = i * 4;
    if (e + 3 < E) {
        int d0 = dst[e], d1 = dst[e + 1], d2 = dst[e + 2], d3 = dst[e + 3];
        int r0 = atomicAdd(&cnt[d0], 1);
        int r1 = atomicAdd(&cnt[d1], 1);
        int r2 = atomicAdd(&cnt[d2], 1);
        int r3 = atomicAdd(&cnt[d3], 1);
        rank[e] = r0; rank[e + 1] = r1; rank[e + 2] = r2; rank[e + 3] = r3;
    } else {
        for (; e < E; ++e) rank[e] = atomicAdd(&cnt[dst[e]], 1);
    }
}

__global__ __launch_bounds__(1024) void scan_part(const int* __restrict__ cnt,
                                                  int* __restrict__ bsum, int Nn) {
    int i = blockIdx.x * 1024 + threadIdx.x;
    int v = (i < Nn) ? cnt[i] : 0;
#pragma unroll
    for (int d = 1; d < 64; d <<= 1) v += __shfl_xor(v, d, 64);
    __shared__ int wsums[16];
    if ((threadIdx.x & 63) == 0) wsums[threadIdx.x >> 6] = v;
    __syncthreads();
    if (threadIdx.x == 0) {
        int s = 0;
        for (int w = 0; w < 16; ++w) s += wsums[w];
        bsum[blockIdx.x] = s;
    }
}

// parallel exclusive scan over NB<=128 block sums (1 block, 128 threads)
__global__ __launch_bounds__(128) void scan_top(int* __restrict__ bsum, int NB) {
    int i = threadIdx.x;
    int v = (i < NB) ? bsum[i] : 0;
    int x = v;
#pragma unroll
    for (int d = 1; d < 64; d <<= 1) {
        int y = __shfl_up(x, d, 64);
        if ((i & 63) >= d) x += y;
    }
    __shared__ int w0;
    if (i == 63) w0 = x;
    __syncthreads();
    if (i >= 64) x += w0;
    if (i < NB) bsum[i] = x - v;
}

__global__ __launch_bounds__(1024) void scan_final(const int* __restrict__ cnt,
                                                   const int* __restrict__ bpre,
                                                   int* __restrict__ offs,
                                                   float* __restrict__ dis, int Nn, int E) {
    int i = blockIdx.x * 1024 + threadIdx.x;
    int v = (i < Nn) ? cnt[i] : 0;
    int lane = threadIdx.x & 63, wid = threadIdx.x >> 6;
    int x = v;
#pragma unroll
    for (int d = 1; d < 64; d <<= 1) {
        int y = __shfl_up(x, d, 64);
        if (lane >= d) x += y;
    }
    __shared__ int wsum[16];
    __shared__ int wpre[16];
    if (lane == 63) wsum[wid] = x;
    __syncthreads();
    if (threadIdx.x == 0) {
        int run = 0;
        for (int w = 0; w < 16; ++w) { wpre[w] = run; run += wsum[w]; }
    }
    __syncthreads();
    int excl = x - v + wpre[wid] + bpre[blockIdx.x];
    if (i < Nn) {
        offs[i] = excl;
        dis[i] = rsqrtf((float)v + 1.0f);
    }
    if (blockIdx.x == 0 && threadIdx.x == 0) offs[Nn] = E;
}

// ---------------- fused fill (4-wide, atomic-free) + cast_scale ----------------
// blocks [0,FB): fill; [FB,FB+CB): tbl[s][c] = bf16(dis[s]*emb[s][c])

__global__ void fill_cast_kernel(const int* __restrict__ src, const int* __restrict__ dst,
                                 const int* __restrict__ rank, const int* __restrict__ offs,
                                 int* __restrict__ rec, int E,
                                 const float4* __restrict__ emb, const float* __restrict__ dis,
                                 ushort4* __restrict__ tbl, int n4, int FB, int CB) {
    if ((int)blockIdx.x < FB) {
        int i = blockIdx.x * 256 + threadIdx.x;
        int e = i * 4;
        if (e + 3 < E) {
            int d0 = dst[e], d1 = dst[e + 1], d2 = dst[e + 2], d3 = dst[e + 3];
            int s0 = src[e], s1 = src[e + 1], s2 = src[e + 2], s3 = src[e + 3];
            int r0 = rank[e], r1 = rank[e + 1], r2 = rank[e + 2], r3 = rank[e + 3];
            int o0 = offs[d0], o1 = offs[d1], o2 = offs[d2], o3 = offs[d3];
            rec[o0 + r0] = s0;
            rec[o1 + r1] = s1;
            rec[o2 + r2] = s2;
            rec[o3 + r3] = s3;
        } else {
            for (; e < E; ++e) rec[offs[dst[e]] + rank[e]] = src[e];
        }
    } else {
        int stride = CB * 256;
        for (int i = ((int)blockIdx.x - FB) * 256 + (int)threadIdx.x; i < n4; i += stride) {
            float s = dis[i >> 5];
            float4 v = emb[i];
            ushort4 o;
            o.x = f2bf(v.x * s); o.y = f2bf(v.y * s); o.z = f2bf(v.z * s); o.w = f2bf(v.w * s);
            tbl[i] = o;
        }
    }
}

// ---------------- aggregation over 128 bf16 cols (pre-scaled table) ----------------
// tbl[s] = dis[s]*x[s] (bf16). out = dn * (tbl[gw] + sum_e tbl[rec[e]])  (+bias)
// one wave per node; lane owns cols {2*lane, 2*lane+1} packed in one uint.
// 8-wide edge batching; tail edges zeroed with one cndmask.

template <bool BIAS, bool BF16OUT>
__global__ __launch_bounds__(256) void agg_kernel(const uint* __restrict__ tbl,   // [Nn][64]
                                                  const int* __restrict__ offs,
                                                  const int* __restrict__ rec,    // src per edge
                                                  const float* __restrict__ dis,
                                                  const float* __restrict__ bias,
                                                  void* __restrict__ outp, int Nn) {
    int gw = (int)((blockIdx.x * 256 + threadIdx.x) >> 6);
    uint lane = threadIdx.x & 63;
    if (gw >= Nn) return;
    float dn = dis[gw];
    int e0 = offs[gw], e1 = offs[gw + 1];
    uint hv = tbl[(uint)gw * 64u + lane];
    float ax = bflo(hv), ay = bfhi(hv);

    for (int base = e0; base < e1; base += 8) {
        uint idx[8];
#pragma unroll
        for (int j = 0; j < 8; ++j) {
            int e = base + j;
            idx[j] = (uint)rec[e < e1 ? e : e1 - 1];
        }
        uint vv[8];
#pragma unroll
        for (int j = 0; j < 8; ++j) vv[j] = tbl[idx[j] * 64u + lane];
#pragma unroll
        for (int j = 0; j < 8; ++j) {
            uint v = (base + j < e1) ? vv[j] : 0u;
            ax += bflo(v);
            ay += bfhi(v);
        }
    }

    ax *= dn; ay *= dn;
    if (BIAS) {
        float2 bv = reinterpret_cast<const float2*>(bias)[lane];
        ax += bv.x; ay += bv.y;
    }
    if (BF16OUT) {
        reinterpret_cast<uint*>(outp)[(uint)gw * 64u + lane] =
            (uint)f2bf(ax) | ((uint)f2bf(ay) << 16);
    } else {
        float2 o; o.x = ax; o.y = ay;
        reinterpret_cast<float2*>(outp)[(uint)gw * 64u + lane] = o;
    }
}

// ---------------- fused MFMA GEMM: x = L2norm(A@W1 + b1); tbl2 = dis * (x@W2) ----------------
// A [M][128] bf16 (agg1 out), W1t [256][128] bf16, W2t [128][256] bf16.
// block = 4 waves, 64-row tile. Stage 1: wave w owns cols [w*64,(w+1)*64) of x;
// epilogue (bias + cross-wave L2 norm) writes x-tile to LDS (XOR-swizzled).
// Stage 2: A-frags from LDS, wave w owns cols [w*32,(w+1)*32) of out; scale by dsc[row].
// mfma_f32_16x16x32_bf16 C/D layout: col=lane&15, row=(lane>>4)*4+reg  [measured m89].

__global__ __launch_bounds__(256) void fused_gemm(const ushort* __restrict__ A,
                                                  const ushort* __restrict__ W1t,
                                                  const float* __restrict__ bias1,
                                                  const ushort* __restrict__ W2t,
                                                  const float* __restrict__ dsc,
                                                  ushort* __restrict__ out2, int M) {
    __shared__ ushort xt[64 * 256];   // 32KB x-tile, elem ^= (row&7)<<3 swizzle
    __shared__ float ssl[4][64];
    int lane = threadIdx.x & 63, wid = threadIdx.x >> 6;
    int m0 = blockIdx.x * 64;
    int koff = (lane >> 4) * 8;

    // ---- stage 1: gemm1 K=128 -> N=256 ----
    const bf16x8* ap[4];
#pragma unroll
    for (int ms = 0; ms < 4; ++ms) {
        int r = m0 + ms * 16 + (lane & 15);
        if (r >= M) r = M - 1;
        ap[ms] = reinterpret_cast<const bf16x8*>(A + (size_t)r * 128 + koff);
    }
    const bf16x8* bp[4];
#pragma unroll
    for (int ns = 0; ns < 4; ++ns) {
        int c = wid * 64 + ns * 16 + (lane & 15);
        bp[ns] = reinterpret_cast<const bf16x8*>(W1t + (size_t)c * 128 + koff);
    }
    f32x4 acc[4][4];
#pragma unroll
    for (int ms = 0; ms < 4; ++ms)
#pragma unroll
        for (int ns = 0; ns < 4; ++ns) acc[ms][ns] = (f32x4){0.f, 0.f, 0.f, 0.f};
#pragma unroll
    for (int ks = 0; ks < 4; ++ks) {
        bf16x8 a[4], b[4];
#pragma unroll
        for (int ms = 0; ms < 4; ++ms) a[ms] = ap[ms][ks * 4];
#pragma unroll
        for (int ns = 0; ns < 4; ++ns) b[ns] = bp[ns][ks * 4];
#pragma unroll
        for (int ms = 0; ms < 4; ++ms)
#pragma unroll
            for (int ns = 0; ns < 4; ++ns)
                acc[ms][ns] = __builtin_amdgcn_mfma_f32_16x16x32_bf16(a[ms], b[ns], acc[ms][ns], 0, 0, 0);
    }

    // bias + row sum-of-squares
    float bv[4];
#pragma unroll
    for (int ns = 0; ns < 4; ++ns) bv[ns] = bias1[wid * 64 + ns * 16 + (lane & 15)];
    float ps[4][4];
#pragma unroll
    for (int ms = 0; ms < 4; ++ms)
#pragma unroll
        for (int r = 0; r < 4; ++r) {
            float s = 0.f;
#pragma unroll
            for (int ns = 0; ns < 4; ++ns) {
                float v = acc[ms][ns][r] + bv[ns];
                acc[ms][ns][r] = v;
                s += v * v;
            }
            ps[ms][r] = s;
        }
#pragma unroll
    for (int d = 1; d < 16; d <<= 1)
#pragma unroll
        for (int ms = 0; ms < 4; ++ms)
#pragma unroll
            for (int r = 0; r < 4; ++r) ps[ms][r] += __shfl_xor(ps[ms][r], d, 64);
    if ((lane & 15) == 0) {
#pragma unroll
        for (int ms = 0; ms < 4; ++ms)
#pragma unroll
            for (int r = 0; r < 4; ++r) ssl[wid][ms * 16 + (lane >> 4) * 4 + r] = ps[ms][r];
    }
    __syncthreads();
    // normalize + write x-tile to LDS (swizzled)
#pragma unroll
    for (int ms = 0; ms < 4; ++ms)
#pragma unroll
        for (int r = 0; r < 4; ++r) {
            int rt = ms * 16 + (lane >> 4) * 4 + r;
            float tot = ssl[0][rt] + ssl[1][rt] + ssl[2][rt] + ssl[3][rt];
            float inv = 1.0f / fmaxf(sqrtf(tot), 1e-12f);
            int sw = (rt & 7) << 3;
#pragma unroll
            for (int ns = 0; ns < 4; ++ns) {
                int col = wid * 64 + ns * 16 + (lane & 15);
                xt[(rt * 256 + col) ^ sw] = f2bf(acc[ms][ns][r] * inv);
            }
        }
    __syncthreads();

    // ---- stage 2: gemm2 K=256 -> N=128, A from LDS ----
    const bf16x8* bp2[2];
#pragma unroll
    for (int ns = 0; ns < 2; ++ns) {
        int c = wid * 32 + ns * 16 + (lane & 15);
        bp2[ns] = reinterpret_cast<const bf16x8*>(W2t + (size_t)c * 256 + koff);
    }
    f32x4 acc2[4][2];
#pragma unroll
    for (int ms = 0; ms < 4; ++ms)
#pragma unroll
        for (int ns = 0; ns < 2; ++ns) acc2[ms][ns] = (f32x4){0.f, 0.f, 0.f, 0.f};
#pragma unroll
    for (int ks = 0; ks < 8; ++ks) {
        bf16x8 a2[4], b2[2];
#pragma unroll
        for (int ms = 0; ms < 4; ++ms) {
            int rowA = ms * 16 + (lane & 15);
            int eb = (rowA * 256 + koff + ks * 32) ^ ((rowA & 7) << 3);
            a2[ms] = *reinterpret_cast<const bf16x8*>(&xt[eb]);
        }
#pragma unroll
        for (int ns = 0; ns < 2; ++ns) b2[ns] = bp2[ns][ks * 4];
#pragma unroll
        for (int ms = 0; ms < 4; ++ms)
#pragma unroll
            for (int ns = 0; ns < 2; ++ns)
                acc2[ms][ns] = __builtin_amdgcn_mfma_f32_16x16x32_bf16(a2[ms], b2[ns], acc2[ms][ns], 0, 0, 0);
    }
    // epilogue: scale rows by dsc, write bf16 gather table
#pragma unroll
    for (int ms = 0; ms < 4; ++ms)
#pragma unroll
        for (int r = 0; r < 4; ++r) {
            int row = m0 + ms * 16 + (lane >> 4) * 4 + r;
            if (row < M) {
                float sc = dsc[row];
#pragma unroll
                for (int ns = 0; ns < 2; ++ns)
                    out2[(size_t)row * 128 + wid * 32 + ns * 16 + (lane & 15)] =
                        f2bf(acc2[ms][ns][r] * sc);
            }
        }
}

// ---------------- launch ----------------

extern "C" void kernel_launch(void* const* d_in, const int* in_sizes, int n_in,
                              void* d_out, int out_size, void* d_ws, size_t ws_size,
                              hipStream_t stream) {
    const float* emb = (const float*)d_in[0];
    const float* W1 = (const float*)d_in[1];
    const float* b1 = (const float*)d_in[2];
    const float* W2 = (const float*)d_in[3];
    const float* b2 = (const float*)d_in[4];
    const int* eidx = (const int*)d_in[5];

    const int Nn = in_sizes[0] / 128;   // 100000
    const int E = in_sizes[5] / 2;      // 1600000
    const int* srcp = eidx;
    const int* dstp = eidx + E;

    float* ws = (float*)d_ws;
    size_t o = 0;
    uint* tbl1 = (uint*)(ws + o);  o += (size_t)Nn * 64;   // dis*emb bf16 [Nn][128]
    uint* axb = (uint*)(ws + o);   o += (size_t)Nn * 64;   // agg1 out bf16 [Nn][128]
    uint* tbl2 = (uint*)(ws + o);  o += (size_t)Nn * 64;   // dis*h2 bf16 [Nn][128]
    ushort* W1t = (ushort*)(ws + o); o += 128 * 256 / 2;   // [256][128]
    ushort* W2t = (ushort*)(ws + o); o += 256 * 128 / 2;   // [128][256]
    float* dis = ws + o;    o += Nn;
    int* cnt = (int*)(ws + o);    o += Nn;
    int* offs = (int*)(ws + o);   o += Nn + 16;
    int* bsum = (int*)(ws + o);   o += 128;
    int* rank = (int*)(ws + o);   o += E;
    int* rec = (int*)(ws + o);    o += E;

    int zb = (Nn + 255) / 256;                 // 391
    prep_kernel<<<zb + 256, 256, 0, stream>>>(W1, W1t, W2, W2t, cnt, Nn, zb);

    int EB = (E + 1023) / 1024;                // 4 edges/thread
    count_kernel<<<EB, 256, 0, stream>>>(dstp, cnt, rank, E);

    int NB = (Nn + 1023) / 1024;               // 98
    scan_part<<<NB, 1024, 0, stream>>>(cnt, bsum, Nn);
    scan_top<<<1, 128, 0, stream>>>(bsum, NB);
    scan_final<<<NB, 1024, 0, stream>>>(cnt, bsum, offs, dis, Nn, E);

    int n4 = Nn * 128 / 4;
    int CB = 2048;
    fill_cast_kernel<<<EB + CB, 256, 0, stream>>>(srcp, dstp, rank, offs, rec, E,
                                                  (const float4*)emb, dis, (ushort4*)tbl1, n4, EB, CB);

    // layer 1: aggregate pre-scaled emb (bf16 out), then fused GEMM1+norm+GEMM2 (+dis scale)
    agg_kernel<false, true><<<(Nn + 3) / 4, 256, 0, stream>>>(tbl1, offs, rec, dis, nullptr, axb, Nn);
    fused_gemm<<<(Nn + 63) / 64, 256, 0, stream>>>((const ushort*)axb, W1t, b1, W2t, dis, (ushort*)tbl2, Nn);

    // layer 2 aggregate + bias (fp32 out)
    agg_kernel<true, false><<<(Nn + 3) / 4, 256, 0, stream>>>(tbl2, offs, rec, dis, b2, d_out, Nn);
}

// Round 7
// 308.997 us; speedup vs baseline: 1.1093x; 1.0008x over previous
//
#include <hip/hip_runtime.h>
#include <hip/hip_bf16.h>

typedef __attribute__((ext_vector_type(8))) short bf16x8;
typedef __attribute__((ext_vector_type(4))) float f32x4;

// ---------------- helpers ----------------

__device__ __forceinline__ ushort f2bf(float f) {
    unsigned int b = __float_as_uint(f);
    unsigned int r = (b + 0x7fffu + ((b >> 16) & 1u)) >> 16;  // RNE
    return (ushort)r;
}
__device__ __forceinline__ float bflo(uint v) { return __uint_as_float(v << 16); }
__device__ __forceinline__ float bfhi(uint v) { return __uint_as_float(v & 0xffff0000u); }

// ---------------- prep: zero cnt + transpose-cast both weights ----------------

__global__ __launch_bounds__(256) void prep_kernel(const float* __restrict__ W1, ushort* __restrict__ W1t,
                                                   const float* __restrict__ W2, ushort* __restrict__ W2t,
                                                   int* __restrict__ cnt, int Nn, int zb) {
    int b = blockIdx.x, t = threadIdx.x;
    if (b < zb) {
        int i = b * 256 + t;
        if (i < Nn) cnt[i] = 0;
    } else if (b < zb + 128) {
        int i = (b - zb) * 256 + t;            // W1t[n][k], n in [0,256), k in [0,128)
        int n = i >> 7, k = i & 127;
        W1t[i] = f2bf(W1[(size_t)k * 256 + n]);
    } else {
        int i = (b - zb - 128) * 256 + t;      // W2t[n][k], n in [0,128), k in [0,256)
        int n = i >> 8, k = i & 255;
        W2t[i] = f2bf(W2[(size_t)k * 128 + n]);
    }
}

// ---------------- CSR build ----------------

// 8 edges/thread: 8 independent atomics in flight, then 8 rank stores
__global__ void count_kernel(const int* __restrict__ dst, int* __restrict__ cnt,
                             int* __restrict__ rank, int E) {
    int i = blockIdx.x * blockDim.x + threadIdx.x;
    int e = i * 8;
    if (e + 7 < E) {
        int d[8], r[8];
#pragma unroll
        for (int j = 0; j < 8; ++j) d[j] = dst[e + j];
#pragma unroll
        for (int j = 0; j < 8; ++j) r[j] = atomicAdd(&cnt[d[j]], 1);
#pragma unroll
        for (int j = 0; j < 8; ++j) rank[e + j] = r[j];
    } else {
        for (; e < E; ++e) rank[e] = atomicAdd(&cnt[dst[e]], 1);
    }
}

__global__ __launch_bounds__(1024) void scan_part(const int* __restrict__ cnt,
                                                  int* __restrict__ bsum, int Nn) {
    int i = blockIdx.x * 1024 + threadIdx.x;
    int v = (i < Nn) ? cnt[i] : 0;
#pragma unroll
    for (int d = 1; d < 64; d <<= 1) v += __shfl_xor(v, d, 64);
    __shared__ int wsums[16];
    if ((threadIdx.x & 63) == 0) wsums[threadIdx.x >> 6] = v;
    __syncthreads();
    if (threadIdx.x == 0) {
        int s = 0;
        for (int w = 0; w < 16; ++w) s += wsums[w];
        bsum[blockIdx.x] = s;
    }
}

// parallel exclusive scan over NB<=128 block sums (1 block, 128 threads)
__global__ __launch_bounds__(128) void scan_top(int* __restrict__ bsum, int NB) {
    int i = threadIdx.x;
    int v = (i < NB) ? bsum[i] : 0;
    int x = v;
#pragma unroll
    for (int d = 1; d < 64; d <<= 1) {
        int y = __shfl_up(x, d, 64);
        if ((i & 63) >= d) x += y;
    }
    __shared__ int w0;
    if (i == 63) w0 = x;
    __syncthreads();
    if (i >= 64) x += w0;
    if (i < NB) bsum[i] = x - v;
}

__global__ __launch_bounds__(1024) void scan_final(const int* __restrict__ cnt,
                                                   const int* __restrict__ bpre,
                                                   int* __restrict__ offs,
                                                   float* __restrict__ dis, int Nn, int E) {
    int i = blockIdx.x * 1024 + threadIdx.x;
    int v = (i < Nn) ? cnt[i] : 0;
    int lane = threadIdx.x & 63, wid = threadIdx.x >> 6;
    int x = v;
#pragma unroll
    for (int d = 1; d < 64; d <<= 1) {
        int y = __shfl_up(x, d, 64);
        if (lane >= d) x += y;
    }
    __shared__ int wsum[16];
    __shared__ int wpre[16];
    if (lane == 63) wsum[wid] = x;
    __syncthreads();
    if (threadIdx.x == 0) {
        int run = 0;
        for (int w = 0; w < 16; ++w) { wpre[w] = run; run += wsum[w]; }
    }
    __syncthreads();
    int excl = x - v + wpre[wid] + bpre[blockIdx.x];
    if (i < Nn) {
        offs[i] = excl;
        dis[i] = rsqrtf((float)v + 1.0f);
    }
    if (blockIdx.x == 0 && threadIdx.x == 0) offs[Nn] = E;
}

// ---------------- fused fill (8-wide, atomic-free) + cast_scale ----------------
// blocks [0,FB): fill; [FB,FB+CB): tbl[s][c] = bf16(dis[s]*emb[s][c])

__global__ void fill_cast_kernel(const int* __restrict__ src, const int* __restrict__ dst,
                                 const int* __restrict__ rank, const int* __restrict__ offs,
                                 int* __restrict__ rec, int E,
                                 const float4* __restrict__ emb, const float* __restrict__ dis,
                                 ushort4* __restrict__ tbl, int n4, int FB, int CB) {
    if ((int)blockIdx.x < FB) {
        int i = blockIdx.x * 256 + threadIdx.x;
        int e = i * 8;
        if (e + 7 < E) {
            int d[8], s[8], r[8], o[8];
#pragma unroll
            for (int j = 0; j < 8; ++j) d[j] = dst[e + j];
#pragma unroll
            for (int j = 0; j < 8; ++j) s[j] = src[e + j];
#pragma unroll
            for (int j = 0; j < 8; ++j) r[j] = rank[e + j];
#pragma unroll
            for (int j = 0; j < 8; ++j) o[j] = offs[d[j]];
#pragma unroll
            for (int j = 0; j < 8; ++j) rec[o[j] + r[j]] = s[j];
        } else {
            for (; e < E; ++e) rec[offs[dst[e]] + rank[e]] = src[e];
        }
    } else {
        int stride = CB * 256;
        for (int i = ((int)blockIdx.x - FB) * 256 + (int)threadIdx.x; i < n4; i += stride) {
            float s = dis[i >> 5];
            float4 v = emb[i];
            ushort4 o;
            o.x = f2bf(v.x * s); o.y = f2bf(v.y * s); o.z = f2bf(v.z * s); o.w = f2bf(v.w * s);
            tbl[i] = o;
        }
    }
}

// ---------------- aggregation over 128 bf16 cols (pre-scaled table) ----------------
// tbl[s] = dis[s]*x[s] (bf16). out = dn * (tbl[gw] + sum_e tbl[rec[e]])  (+bias)
// one wave per node; lane owns cols {2*lane, 2*lane+1} packed in one uint.
// 8-wide edge batching; tail edges zeroed with one cndmask.

template <bool BIAS, bool BF16OUT>
__global__ __launch_bounds__(256) void agg_kernel(const uint* __restrict__ tbl,   // [Nn][64]
                                                  const int* __restrict__ offs,
                                                  const int* __restrict__ rec,    // src per edge
                                                  const float* __restrict__ dis,
                                                  const float* __restrict__ bias,
                                                  void* __restrict__ outp, int Nn) {
    int gw = (int)((blockIdx.x * 256 + threadIdx.x) >> 6);
    uint lane = threadIdx.x & 63;
    if (gw >= Nn) return;
    float dn = dis[gw];
    int e0 = offs[gw], e1 = offs[gw + 1];
    uint hv = tbl[(uint)gw * 64u + lane];
    float ax = bflo(hv), ay = bfhi(hv);

    for (int base = e0; base < e1; base += 8) {
        uint idx[8];
#pragma unroll
        for (int j = 0; j < 8; ++j) {
            int e = base + j;
            idx[j] = (uint)rec[e < e1 ? e : e1 - 1];
        }
        uint vv[8];
#pragma unroll
        for (int j = 0; j < 8; ++j) vv[j] = tbl[idx[j] * 64u + lane];
#pragma unroll
        for (int j = 0; j < 8; ++j) {
            uint v = (base + j < e1) ? vv[j] : 0u;
            ax += bflo(v);
            ay += bfhi(v);
        }
    }

    ax *= dn; ay *= dn;
    if (BIAS) {
        float2 bv = reinterpret_cast<const float2*>(bias)[lane];
        ax += bv.x; ay += bv.y;
    }
    if (BF16OUT) {
        reinterpret_cast<uint*>(outp)[(uint)gw * 64u + lane] =
            (uint)f2bf(ax) | ((uint)f2bf(ay) << 16);
    } else {
        float2 o; o.x = ax; o.y = ay;
        reinterpret_cast<float2*>(outp)[(uint)gw * 64u + lane] = o;
    }
}

// ---------------- fused MFMA GEMM: x = L2norm(A@W1 + b1); tbl2 = dis * (x@W2) ----------------
// A [M][128] bf16 (agg1 out), W1t [256][128] bf16, W2t [128][256] bf16.
// block = 4 waves, 64-row tile. All 32 stage-1 fragment loads hoisted (single
// latency window); W2 fragment loads issued under the stage-1 epilogue.
// __launch_bounds__(256,2): cap 256 VGPR so all fragments stay in flight.
// mfma_f32_16x16x32_bf16 C/D layout: col=lane&15, row=(lane>>4)*4+reg  [measured m89].

__global__ __launch_bounds__(256, 2) void fused_gemm(const ushort* __restrict__ A,
                                                     const ushort* __restrict__ W1t,
                                                     const float* __restrict__ bias1,
                                                     const ushort* __restrict__ W2t,
                                                     const float* __restrict__ dsc,
                                                     ushort* __restrict__ out2, int M) {
    __shared__ ushort xt[64 * 256];   // 32KB x-tile, elem ^= (row&7)<<3 swizzle
    __shared__ float ssl[4][64];
    int lane = threadIdx.x & 63, wid = threadIdx.x >> 6;
    int m0 = blockIdx.x * 64;
    int koff = (lane >> 4) * 8;

    // ---- stage 1: gemm1 K=128 -> N=256 ----
    bf16x8 a[4][4], b1f[4][4];
#pragma unroll
    for (int ms = 0; ms < 4; ++ms) {
        int r = m0 + ms * 16 + (lane & 15);
        if (r >= M) r = M - 1;
        const bf16x8* p = reinterpret_cast<const bf16x8*>(A + (size_t)r * 128 + koff);
#pragma unroll
        for (int ks = 0; ks < 4; ++ks) a[ms][ks] = p[ks * 4];
    }
#pragma unroll
    for (int ns = 0; ns < 4; ++ns) {
        int c = wid * 64 + ns * 16 + (lane & 15);
        const bf16x8* p = reinterpret_cast<const bf16x8*>(W1t + (size_t)c * 128 + koff);
#pragma unroll
        for (int ks = 0; ks < 4; ++ks) b1f[ns][ks] = p[ks * 4];
    }

    f32x4 acc[4][4];
#pragma unroll
    for (int ms = 0; ms < 4; ++ms)
#pragma unroll
        for (int ns = 0; ns < 4; ++ns) acc[ms][ns] = (f32x4){0.f, 0.f, 0.f, 0.f};
#pragma unroll
    for (int ks = 0; ks < 4; ++ks)
#pragma unroll
        for (int ms = 0; ms < 4; ++ms)
#pragma unroll
            for (int ns = 0; ns < 4; ++ns)
                acc[ms][ns] = __builtin_amdgcn_mfma_f32_16x16x32_bf16(a[ms][ks], b1f[ns][ks], acc[ms][ns], 0, 0, 0);

    // issue W2 fragment loads now: latency hides under the epilogue below
    bf16x8 b2f[2][8];
#pragma unroll
    for (int ns = 0; ns < 2; ++ns) {
        int c = wid * 32 + ns * 16 + (lane & 15);
        const bf16x8* p = reinterpret_cast<const bf16x8*>(W2t + (size_t)c * 256 + koff);
#pragma unroll
        for (int ks = 0; ks < 8; ++ks) b2f[ns][ks] = p[ks * 4];
    }

    // bias + row sum-of-squares
    float bv[4];
#pragma unroll
    for (int ns = 0; ns < 4; ++ns) bv[ns] = bias1[wid * 64 + ns * 16 + (lane & 15)];
    float ps[4][4];
#pragma unroll
    for (int ms = 0; ms < 4; ++ms)
#pragma unroll
        for (int r = 0; r < 4; ++r) {
            float s = 0.f;
#pragma unroll
            for (int ns = 0; ns < 4; ++ns) {
                float v = acc[ms][ns][r] + bv[ns];
                acc[ms][ns][r] = v;
                s += v * v;
            }
            ps[ms][r] = s;
        }
#pragma unroll
    for (int d = 1; d < 16; d <<= 1)
#pragma unroll
        for (int ms = 0; ms < 4; ++ms)
#pragma unroll
            for (int r = 0; r < 4; ++r) ps[ms][r] += __shfl_xor(ps[ms][r], d, 64);
    if ((lane & 15) == 0) {
#pragma unroll
        for (int ms = 0; ms < 4; ++ms)
#pragma unroll
            for (int r = 0; r < 4; ++r) ssl[wid][ms * 16 + (lane >> 4) * 4 + r] = ps[ms][r];
    }
    __syncthreads();
    // normalize + write x-tile to LDS (swizzled)
#pragma unroll
    for (int ms = 0; ms < 4; ++ms)
#pragma unroll
        for (int r = 0; r < 4; ++r) {
            int rt = ms * 16 + (lane >> 4) * 4 + r;
            float tot = ssl[0][rt] + ssl[1][rt] + ssl[2][rt] + ssl[3][rt];
            float inv = 1.0f / fmaxf(sqrtf(tot), 1e-12f);
            int sw = (rt & 7) << 3;
#pragma unroll
            for (int ns = 0; ns < 4; ++ns) {
                int col = wid * 64 + ns * 16 + (lane & 15);
                xt[(rt * 256 + col) ^ sw] = f2bf(acc[ms][ns][r] * inv);
            }
        }
    __syncthreads();

    // ---- stage 2: gemm2 K=256 -> N=128, A from LDS ----
    f32x4 acc2[4][2];
#pragma unroll
    for (int ms = 0; ms < 4; ++ms)
#pragma unroll
        for (int ns = 0; ns < 2; ++ns) acc2[ms][ns] = (f32x4){0.f, 0.f, 0.f, 0.f};
#pragma unroll
    for (int ks = 0; ks < 8; ++ks) {
        bf16x8 a2[4];
#pragma unroll
        for (int ms = 0; ms < 4; ++ms) {
            int rowA = ms * 16 + (lane & 15);
            int eb = (rowA * 256 + koff + ks * 32) ^ ((rowA & 7) << 3);
            a2[ms] = *reinterpret_cast<const bf16x8*>(&xt[eb]);
        }
#pragma unroll
        for (int ms = 0; ms < 4; ++ms)
#pragma unroll
            for (int ns = 0; ns < 2; ++ns)
                acc2[ms][ns] = __builtin_amdgcn_mfma_f32_16x16x32_bf16(a2[ms], b2f[ns][ks], acc2[ms][ns], 0, 0, 0);
    }
    // epilogue: scale rows by dsc, write bf16 gather table
#pragma unroll
    for (int ms = 0; ms < 4; ++ms)
#pragma unroll
        for (int r = 0; r < 4; ++r) {
            int row = m0 + ms * 16 + (lane >> 4) * 4 + r;
            if (row < M) {
                float sc = dsc[row];
#pragma unroll
                for (int ns = 0; ns < 2; ++ns)
                    out2[(size_t)row * 128 + wid * 32 + ns * 16 + (lane & 15)] =
                        f2bf(acc2[ms][ns][r] * sc);
            }
        }
}

// ---------------- launch ----------------

extern "C" void kernel_launch(void* const* d_in, const int* in_sizes, int n_in,
                              void* d_out, int out_size, void* d_ws, size_t ws_size,
                              hipStream_t stream) {
    const float* emb = (const float*)d_in[0];
    const float* W1 = (const float*)d_in[1];
    const float* b1 = (const float*)d_in[2];
    const float* W2 = (const float*)d_in[3];
    const float* b2 = (const float*)d_in[4];
    const int* eidx = (const int*)d_in[5];

    const int Nn = in_sizes[0] / 128;   // 100000
    const int E = in_sizes[5] / 2;      // 1600000
    const int* srcp = eidx;
    const int* dstp = eidx + E;

    float* ws = (float*)d_ws;
    size_t o = 0;
    uint* tbl1 = (uint*)(ws + o);  o += (size_t)Nn * 64;   // dis*emb bf16 [Nn][128]
    uint* axb = (uint*)(ws + o);   o += (size_t)Nn * 64;   // agg1 out bf16 [Nn][128]
    uint* tbl2 = (uint*)(ws + o);  o += (size_t)Nn * 64;   // dis*h2 bf16 [Nn][128]
    ushort* W1t = (ushort*)(ws + o); o += 128 * 256 / 2;   // [256][128]
    ushort* W2t = (ushort*)(ws + o); o += 256 * 128 / 2;   // [128][256]
    float* dis = ws + o;    o += Nn;
    int* cnt = (int*)(ws + o);    o += Nn;
    int* offs = (int*)(ws + o);   o += Nn + 16;
    int* bsum = (int*)(ws + o);   o += 128;
    int* rank = (int*)(ws + o);   o += E;
    int* rec = (int*)(ws + o);    o += E;

    int zb = (Nn + 255) / 256;                 // 391
    prep_kernel<<<zb + 256, 256, 0, stream>>>(W1, W1t, W2, W2t, cnt, Nn, zb);

    int EBc = (E + 2047) / 2048;               // 8 edges/thread
    count_kernel<<<EBc, 256, 0, stream>>>(dstp, cnt, rank, E);

    int NB = (Nn + 1023) / 1024;               // 98
    scan_part<<<NB, 1024, 0, stream>>>(cnt, bsum, Nn);
    scan_top<<<1, 128, 0, stream>>>(bsum, NB);
    scan_final<<<NB, 1024, 0, stream>>>(cnt, bsum, offs, dis, Nn, E);

    int n4 = Nn * 128 / 4;
    int CB = 2048;
    int FB = (E + 2047) / 2048;                // 8 edges/thread fill
    fill_cast_kernel<<<FB + CB, 256, 0, stream>>>(srcp, dstp, rank, offs, rec, E,
                                                  (const float4*)emb, dis, (ushort4*)tbl1, n4, FB, CB);

    // layer 1: aggregate pre-scaled emb (bf16 out), then fused GEMM1+norm+GEMM2 (+dis scale)
    agg_kernel<false, true><<<(Nn + 3) / 4, 256, 0, stream>>>(tbl1, offs, rec, dis, nullptr, axb, Nn);
    fused_gemm<<<(Nn + 63) / 64, 256, 0, stream>>>((const ushort*)axb, W1t, b1, W2t, dis, (ushort*)tbl2, Nn);

    // layer 2 aggregate + bias (fp32 out)
    agg_kernel<true, false><<<(Nn + 3) / 4, 256, 0, stream>>>(tbl2, offs, rec, dis, b2, d_out, Nn);
}